// Round 14
// baseline (280.296 us; speedup 1.0000x reference)
//
#include <hip/hip_runtime.h>

#define N_NODES 100000
#define N_EDGES 1600000
#define FDIM 64
#define NGRAPH 512
#define NB 782          // dst buckets of 128 nodes
#define NBP 784         // padded pitch for wg-major hist rows
#define NWG 512         // workgroups in hist/bin passes
#define CHUNK 3125      // E / NWG
#define DWG 64          // workgroups for degree binning
#define DCHUNK ((N_NODES + DWG - 1) / DWG)
#define MAXD 128        // degree clamp for counting sort
#define GMAX 8          // max graphs spanned by a 128-node window

__device__ __forceinline__ unsigned short f2bf(float v) {
    unsigned int x = __float_as_uint(v);
    x += 0x7FFF + ((x >> 16) & 1);          // RTNE
    return (unsigned short)(x >> 16);
}
#define BFLO(u) __uint_as_float((u) << 16)
#define BFHI(u) __uint_as_float((u) & 0xFFFF0000u)

// ================= scan kernels =================
__global__ void scan_block(const int* __restrict__ in, int* __restrict__ excl,
                           int* __restrict__ blocksums, int n) {
    __shared__ int lds[256];
    int t = threadIdx.x;
    int base = blockIdx.x * 1024 + t * 4;
    int v0 = (base     < n) ? in[base]     : 0;
    int v1 = (base + 1 < n) ? in[base + 1] : 0;
    int v2 = (base + 2 < n) ? in[base + 2] : 0;
    int v3 = (base + 3 < n) ? in[base + 3] : 0;
    int s = v0 + v1 + v2 + v3;
    lds[t] = s;
    __syncthreads();
    for (int off = 1; off < 256; off <<= 1) {
        int x = (t >= off) ? lds[t - off] : 0;
        __syncthreads();
        lds[t] += x;
        __syncthreads();
    }
    int thrExcl = lds[t] - s;
    if (t == 255) blocksums[blockIdx.x] = lds[255];
    if (base     < n) excl[base]     = thrExcl;
    if (base + 1 < n) excl[base + 1] = thrExcl + v0;
    if (base + 2 < n) excl[base + 2] = thrExcl + v0 + v1;
    if (base + 3 < n) excl[base + 3] = thrExcl + v0 + v1 + v2;
}

__global__ void scan_top2(int* __restrict__ blocksums, int nb) {
    __shared__ int lds[256];
    int t = threadIdx.x;
    int base = t * 4;
    int v0 = (base     < nb) ? blocksums[base]     : 0;
    int v1 = (base + 1 < nb) ? blocksums[base + 1] : 0;
    int v2 = (base + 2 < nb) ? blocksums[base + 2] : 0;
    int v3 = (base + 3 < nb) ? blocksums[base + 3] : 0;
    int s = v0 + v1 + v2 + v3;
    lds[t] = s;
    __syncthreads();
    for (int off = 1; off < 256; off <<= 1) {
        int x = (t >= off) ? lds[t - off] : 0;
        __syncthreads();
        lds[t] += x;
        __syncthreads();
    }
    int excl = lds[t] - s;
    if (base     < nb) blocksums[base]     = excl;
    if (base + 1 < nb) blocksums[base + 1] = excl + v0;
    if (base + 2 < nb) blocksums[base + 2] = excl + v0 + v1;
    if (base + 3 < nb) blocksums[base + 3] = excl + v0 + v1 + v2;
}

__global__ void scan_add(int* __restrict__ out, const int* __restrict__ blocksums, int n) {
    int i = blockIdx.x * blockDim.x + threadIdx.x;
    if (i < n) out[i] += blocksums[i >> 10];
}

// single-block exclusive scan for n = 8192 (degree histogram)
__global__ __launch_bounds__(256) void scan_single(int* __restrict__ data, int n) {
    __shared__ int lds[256];
    int t = threadIdx.x;
    int loc[32];
    int base = t * 32;
    int s = 0;
    #pragma unroll
    for (int j = 0; j < 32; ++j) { loc[j] = (base + j < n) ? data[base + j] : 0; s += loc[j]; }
    lds[t] = s;
    __syncthreads();
    for (int off = 1; off < 256; off <<= 1) {
        int x = (t >= off) ? lds[t - off] : 0;
        __syncthreads();
        lds[t] += x;
        __syncthreads();
    }
    int run = lds[t] - s;
    #pragma unroll
    for (int j = 0; j < 32; ++j) {
        int v = loc[j];
        if (base + j < n) data[base + j] = run;
        run += v;
    }
}

// ================= 32x32 LDS transpose =================
__global__ __launch_bounds__(256) void transpose_k(const int* __restrict__ src, int* __restrict__ dst,
                                                   int R, int C, int spitch, int dpitch) {
    __shared__ int tile[32][33];
    int tilesC = (C + 31) >> 5;
    int bx = blockIdx.x % tilesC;
    int by = blockIdx.x / tilesC;
    int tx = threadIdx.x & 31, ty = threadIdx.x >> 5;
    int c = bx * 32 + tx;
    #pragma unroll
    for (int j = 0; j < 32; j += 8) {
        int r = by * 32 + ty + j;
        if (r < R && c < C) tile[ty + j][tx] = src[r * spitch + c];
    }
    __syncthreads();
    int rT = by * 32 + tx;
    #pragma unroll
    for (int j = 0; j < 32; j += 8) {
        int cT = bx * 32 + ty + j;
        if (cT < C && rT < R) dst[cT * dpitch + rT] = tile[tx][ty + j];
    }
}

// ================= pass A: per-wg bucket histogram (wg-major, coalesced) =================
__global__ __launch_bounds__(256) void hist_kernel(const int* __restrict__ dst,
                                                   int* __restrict__ histWG, int E) {
    __shared__ int h[NB];
    int t = threadIdx.x, wg = blockIdx.x;
    for (int i = t; i < NB; i += 256) h[i] = 0;
    __syncthreads();
    int beg = wg * CHUNK, end = min(beg + CHUNK, E);
    for (int i = beg + t; i < end; i += 256) atomicAdd(&h[dst[i] >> 7], 1);
    __syncthreads();
    for (int i = t; i < NB; i += 256) histWG[wg * NBP + i] = h[i];
}

// ================= pass B: binned append =================
__global__ __launch_bounds__(256) void bin_kernel(const int* __restrict__ src,
                                                  const int* __restrict__ dst,
                                                  const int* __restrict__ baseWG,
                                                  int* __restrict__ ebin, int E) {
    __shared__ int base[NB];
    __shared__ int cur[NB];
    int t = threadIdx.x, wg = blockIdx.x;
    for (int i = t; i < NB; i += 256) { base[i] = baseWG[wg * NBP + i]; cur[i] = 0; }
    __syncthreads();
    int beg = wg * CHUNK, end = min(beg + CHUNK, E);
    for (int i = beg + t * 2; i < end; i += 512) {
        int d0 = dst[i], s0 = src[i];
        int b0 = d0 >> 7;
        int p0 = base[b0] + atomicAdd(&cur[b0], 1);
        ebin[p0] = ((d0 & 127) << 17) | s0;
        if (i + 1 < end) {
            int d1 = dst[i + 1], s1 = src[i + 1];
            int b1 = d1 >> 7;
            int p1 = base[b1] + atomicAdd(&cur[b1], 1);
            ebin[p1] = ((d1 & 127) << 17) | s1;
        }
    }
}

// ================= pass C: per-bucket sort + degree + dinv + offsets =================
__global__ __launch_bounds__(256) void csr_sort2(const int* __restrict__ ebin,
                                                 const int* __restrict__ scannedT,
                                                 int* __restrict__ csr_src,
                                                 int* __restrict__ offsets,
                                                 float* __restrict__ dinv, int E) {
    __shared__ int cnt[128];
    __shared__ int seg[128];
    __shared__ int cur[128];
    __shared__ int buf[4352];
    int t = threadIdx.x, b = blockIdx.x;
    int nbase = b << 7;
    int nodes = min(128, N_NODES - nbase);
    int bstart = scannedT[b * NWG];
    int bend = (b == NB - 1) ? E : scannedT[(b + 1) * NWG];
    if (t < 128) cnt[t] = 0;
    __syncthreads();
    for (int i = bstart + t; i < bend; i += 256) atomicAdd(&cnt[ebin[i] >> 17], 1);
    __syncthreads();
    if (t < 128) seg[t] = cnt[t];
    __syncthreads();
    for (int off = 1; off < 128; off <<= 1) {
        int v = 0;
        if (t < 128 && t >= off) v = seg[t - off];
        __syncthreads();
        if (t < 128) seg[t] += v;
        __syncthreads();
    }
    if (t < nodes) {
        int excl = seg[t] - cnt[t];
        offsets[nbase + t] = bstart + excl;
        dinv[nbase + t] = rsqrtf((float)cnt[t] + 1.0f);   // +1 self loop
        cur[t] = excl;
    }
    if (b == 0 && t == 0) offsets[N_NODES] = E;
    __syncthreads();
    for (int i = bstart + t; i < bend; i += 256) {
        int v = ebin[i];
        int p = atomicAdd(&cur[v >> 17], 1);
        buf[p] = v & 0x1FFFF;
    }
    __syncthreads();
    int span = bend - bstart;
    for (int i = t; i < span; i += 256) csr_src[bstart + i] = buf[i];
}

// ================= degree counting sort =================
__global__ __launch_bounds__(256) void histD_kernel(const int* __restrict__ offsets,
                                                    int* __restrict__ histD) {
    __shared__ int h[MAXD];
    int t = threadIdx.x, wg = blockIdx.x;
    if (t < MAXD) h[t] = 0;
    __syncthreads();
    int beg = wg * DCHUNK, end = min(beg + DCHUNK, N_NODES);
    for (int i = beg + t; i < end; i += 256) {
        int d = min(offsets[i + 1] - offsets[i], MAXD - 1);
        atomicAdd(&h[d], 1);
    }
    __syncthreads();
    if (t < MAXD) histD[t * DWG + wg] = h[t];
}

__global__ __launch_bounds__(256) void binD_kernel(const int* __restrict__ offsets,
                                                   const int* __restrict__ scannedD,
                                                   int* __restrict__ perm) {
    __shared__ int base[MAXD];
    __shared__ int cur[MAXD];
    int t = threadIdx.x, wg = blockIdx.x;
    if (t < MAXD) { base[t] = scannedD[t * DWG + wg]; cur[t] = 0; }
    __syncthreads();
    int beg = wg * DCHUNK, end = min(beg + DCHUNK, N_NODES);
    for (int i = beg + t; i < end; i += 256) {
        int d = min(offsets[i + 1] - offsets[i], MAXD - 1);
        int pos = base[d] + atomicAdd(&cur[d], 1);
        perm[pos] = i;
    }
}

// ================= fp32 GEMM (register-tiled 4x4) -> bf16 =================
__global__ __launch_bounds__(256) void gemm64(const float* __restrict__ X,
                                              const float* __restrict__ W,
                                              const float* __restrict__ dinv,
                                              unsigned short* __restrict__ Hout, int n) {
    __shared__ float Ws[64 * 68];
    __shared__ float Xs[64 * 68];
    int t = threadIdx.x;
    int r0 = blockIdx.x * 64;

    #pragma unroll
    for (int kk = 0; kk < 16; ++kk) {
        int idx = t + kk * 256;
        int r = idx >> 6, c = idx & 63;
        Ws[r * 68 + c] = W[idx];
        float v = (r0 + r < n) ? X[(size_t)(r0 + r) * FDIM + c] : 0.0f;
        Xs[c * 68 + r] = v;
    }
    __syncthreads();

    int rg = (t >> 4) << 2;
    int cg = (t & 15) << 2;
    float4 acc0 = {0, 0, 0, 0}, acc1 = {0, 0, 0, 0};
    float4 acc2 = {0, 0, 0, 0}, acc3 = {0, 0, 0, 0};

    #pragma unroll 8
    for (int k = 0; k < 64; ++k) {
        float4 xv = *(const float4*)&Xs[k * 68 + rg];
        float4 wv = *(const float4*)&Ws[k * 68 + cg];
        acc0.x += xv.x * wv.x; acc0.y += xv.x * wv.y; acc0.z += xv.x * wv.z; acc0.w += xv.x * wv.w;
        acc1.x += xv.y * wv.x; acc1.y += xv.y * wv.y; acc1.z += xv.y * wv.z; acc1.w += xv.y * wv.w;
        acc2.x += xv.z * wv.x; acc2.y += xv.z * wv.y; acc2.z += xv.z * wv.z; acc2.w += xv.z * wv.w;
        acc3.x += xv.w * wv.x; acc3.y += xv.w * wv.y; acc3.z += xv.w * wv.z; acc3.w += xv.w * wv.w;
    }

    float4 accs[4] = {acc0, acc1, acc2, acc3};
    #pragma unroll
    for (int i = 0; i < 4; ++i) {
        int row = r0 + rg + i;
        if (row < n) {
            float sc = dinv[row];
            unsigned int u0 = (unsigned int)f2bf(accs[i].x * sc) | ((unsigned int)f2bf(accs[i].y * sc) << 16);
            unsigned int u1 = (unsigned int)f2bf(accs[i].z * sc) | ((unsigned int)f2bf(accs[i].w * sc) << 16);
            *(uint2*)&Hout[(size_t)row * FDIM + cg] = make_uint2(u0, u1);
        }
    }
}

// ================= gather, 8 lanes own one node, unroll-8 =================
#define ACC8(v) do { \
    a0 += BFLO(v.x); a1 += BFHI(v.x); a2 += BFLO(v.y); a3 += BFHI(v.y); \
    a4 += BFLO(v.z); a5 += BFHI(v.z); a6 += BFLO(v.w); a7 += BFHI(v.w); } while (0)

__global__ __launch_bounds__(256) void gather_pn(const unsigned short* __restrict__ hs,
                                                 const int* __restrict__ csr_src,
                                                 const int* __restrict__ offsets,
                                                 const int* __restrict__ perm,
                                                 const float* __restrict__ dinv,
                                                 const float* __restrict__ bias,
                                                 float* __restrict__ outb,
                                                 int n, int do_relu) {
    int slot = (blockIdx.x * 256 + threadIdx.x) >> 3;
    int p = threadIdx.x & 7;
    if (slot >= n) return;
    int node = perm[slot];
    int beg = offsets[node], end = offsets[node + 1];

    float a0 = 0, a1 = 0, a2 = 0, a3 = 0, a4 = 0, a5 = 0, a6 = 0, a7 = 0;
    int k = beg;
    for (; k + 7 < end; k += 8) {
        int s0 = csr_src[k],     s1 = csr_src[k + 1], s2 = csr_src[k + 2], s3 = csr_src[k + 3];
        int s4 = csr_src[k + 4], s5 = csr_src[k + 5], s6 = csr_src[k + 6], s7 = csr_src[k + 7];
        uint4 v0 = *(const uint4*)(hs + ((size_t)s0 << 6) + (p << 3));
        uint4 v1 = *(const uint4*)(hs + ((size_t)s1 << 6) + (p << 3));
        uint4 v2 = *(const uint4*)(hs + ((size_t)s2 << 6) + (p << 3));
        uint4 v3 = *(const uint4*)(hs + ((size_t)s3 << 6) + (p << 3));
        uint4 v4 = *(const uint4*)(hs + ((size_t)s4 << 6) + (p << 3));
        uint4 v5 = *(const uint4*)(hs + ((size_t)s5 << 6) + (p << 3));
        uint4 v6 = *(const uint4*)(hs + ((size_t)s6 << 6) + (p << 3));
        uint4 v7 = *(const uint4*)(hs + ((size_t)s7 << 6) + (p << 3));
        ACC8(v0); ACC8(v1); ACC8(v2); ACC8(v3);
        ACC8(v4); ACC8(v5); ACC8(v6); ACC8(v7);
    }
    for (; k + 3 < end; k += 4) {
        int s0 = csr_src[k], s1 = csr_src[k + 1], s2 = csr_src[k + 2], s3 = csr_src[k + 3];
        uint4 v0 = *(const uint4*)(hs + ((size_t)s0 << 6) + (p << 3));
        uint4 v1 = *(const uint4*)(hs + ((size_t)s1 << 6) + (p << 3));
        uint4 v2 = *(const uint4*)(hs + ((size_t)s2 << 6) + (p << 3));
        uint4 v3 = *(const uint4*)(hs + ((size_t)s3 << 6) + (p << 3));
        ACC8(v0); ACC8(v1); ACC8(v2); ACC8(v3);
    }
    for (; k < end; ++k) {
        int s0 = csr_src[k];
        uint4 v0 = *(const uint4*)(hs + ((size_t)s0 << 6) + (p << 3));
        ACC8(v0);
    }
    // self-loop row
    uint4 sv = *(const uint4*)(hs + ((size_t)node << 6) + (p << 3));
    float dd = dinv[node];
    int fb = p << 3;
    const float4* bp = (const float4*)(bias + fb);
    float4 bv0 = bp[0], bv1 = bp[1];
    float o0 = dd * (a0 + BFLO(sv.x)) + bv0.x;
    float o1 = dd * (a1 + BFHI(sv.x)) + bv0.y;
    float o2 = dd * (a2 + BFLO(sv.y)) + bv0.z;
    float o3 = dd * (a3 + BFHI(sv.y)) + bv0.w;
    float o4 = dd * (a4 + BFLO(sv.z)) + bv1.x;
    float o5 = dd * (a5 + BFHI(sv.z)) + bv1.y;
    float o6 = dd * (a6 + BFLO(sv.w)) + bv1.z;
    float o7 = dd * (a7 + BFHI(sv.w)) + bv1.w;
    if (do_relu) {
        o0 = fmaxf(o0, 0.0f); o1 = fmaxf(o1, 0.0f); o2 = fmaxf(o2, 0.0f); o3 = fmaxf(o3, 0.0f);
        o4 = fmaxf(o4, 0.0f); o5 = fmaxf(o5, 0.0f); o6 = fmaxf(o6, 0.0f); o7 = fmaxf(o7, 0.0f);
    }
    float4* op = (float4*)(outb + (size_t)node * FDIM + fb);
    op[0] = make_float4(o0, o1, o2, o3);
    op[1] = make_float4(o4, o5, o6, o7);
}

// ================= layer-3 fused gather+pool (unroll-4 for MLP) =================
#define POOLACC(r, v) do { \
    int l_ = (v) >> 17; float w_ = dinv_l[l_]; int g_ = gl[l_]; \
    float f0_ = BFLO(r.x), f1_ = BFHI(r.x), f2_ = BFLO(r.y), f3_ = BFHI(r.y); \
    float f4_ = BFLO(r.z), f5_ = BFHI(r.z), f6_ = BFLO(r.w), f7_ = BFHI(r.w); \
    float w0_ = (g_ == 0) ? w_ : 0.0f; \
    float w1_ = (g_ == 1) ? w_ : 0.0f; \
    a0[0] += w0_ * f0_; a0[1] += w0_ * f1_; a0[2] += w0_ * f2_; a0[3] += w0_ * f3_; \
    a0[4] += w0_ * f4_; a0[5] += w0_ * f5_; a0[6] += w0_ * f6_; a0[7] += w0_ * f7_; \
    a1[0] += w1_ * f0_; a1[1] += w1_ * f1_; a1[2] += w1_ * f2_; a1[3] += w1_ * f3_; \
    a1[4] += w1_ * f4_; a1[5] += w1_ * f5_; a1[6] += w1_ * f6_; a1[7] += w1_ * f7_; \
    if (g_ >= 2) { \
        atomicAdd(&tg[g_][p * 8 + 0], w_ * f0_); atomicAdd(&tg[g_][p * 8 + 1], w_ * f1_); \
        atomicAdd(&tg[g_][p * 8 + 2], w_ * f2_); atomicAdd(&tg[g_][p * 8 + 3], w_ * f3_); \
        atomicAdd(&tg[g_][p * 8 + 4], w_ * f4_); atomicAdd(&tg[g_][p * 8 + 5], w_ * f5_); \
        atomicAdd(&tg[g_][p * 8 + 6], w_ * f6_); atomicAdd(&tg[g_][p * 8 + 7], w_ * f7_); \
    } } while (0)

__global__ __launch_bounds__(256) void gather_pool(const unsigned short* __restrict__ zs,
                                                   const int* __restrict__ ebin,
                                                   const int* __restrict__ bucketBase, // histT, stride NWG
                                                   const float* __restrict__ dinv,
                                                   const int* __restrict__ batch,
                                                   float* __restrict__ tpool, int E) {
    __shared__ float dinv_l[128];
    __shared__ int   gl[128];
    __shared__ float tg[GMAX][64];
    __shared__ int   gmin_s;
    int t = threadIdx.x;
    int b = blockIdx.x >> 1;
    int half = blockIdx.x & 1;
    int nbase = b << 7;
    int nodes = min(128, N_NODES - nbase);
    int bstart = bucketBase[b * NWG];
    int bend   = (b == NB - 1) ? E : bucketBase[(b + 1) * NWG];

    if (t == 0) gmin_s = batch[nbase];
    for (int i = t; i < GMAX * 64; i += 256) ((float*)tg)[i] = 0.0f;
    __syncthreads();
    int gmin = gmin_s;
    if (t < 128) {
        dinv_l[t] = (t < nodes) ? dinv[nbase + t] : 0.0f;
        gl[t]     = (t < nodes) ? (batch[nbase + t] - gmin) : 0;
    }
    __syncthreads();

    int s = t >> 3, p = t & 7;           // 32 edge slots x 8 feature octets
    float a0[8], a1[8];
    #pragma unroll
    for (int j = 0; j < 8; ++j) { a0[j] = 0.0f; a1[j] = 0.0f; }

    int span = bend - bstart;
    int hbeg = bstart + half * (span >> 1);
    int hend = (half == 0) ? (bstart + (span >> 1)) : bend;
    int len = hend - hbeg;
    const int* ep = ebin + hbeg;
    int nfull = len >> 7;                // 128-edge chunks: slot s owns e..e+3

    for (int c = 0; c < nfull; ++c) {
        int e = (c << 7) + (s << 2);
        int v0 = ep[e], v1 = ep[e + 1], v2 = ep[e + 2], v3 = ep[e + 3];
        uint4 r0 = *(const uint4*)(zs + ((size_t)(v0 & 0x1FFFF) << 6) + (p << 3));
        uint4 r1 = *(const uint4*)(zs + ((size_t)(v1 & 0x1FFFF) << 6) + (p << 3));
        uint4 r2 = *(const uint4*)(zs + ((size_t)(v2 & 0x1FFFF) << 6) + (p << 3));
        uint4 r3 = *(const uint4*)(zs + ((size_t)(v3 & 0x1FFFF) << 6) + (p << 3));
        POOLACC(r0, v0); POOLACC(r1, v1); POOLACC(r2, v2); POOLACC(r3, v3);
    }
    for (int e = (nfull << 7) + s; e < len; e += 32) {
        int v = ep[e];
        uint4 r = *(const uint4*)(zs + ((size_t)(v & 0x1FFFF) << 6) + (p << 3));
        POOLACC(r, v);
    }

    // self-loops: half 0 -> locals 0..63, half 1 -> 64..127
    for (int l = half * 64 + s; l < min(nodes, half * 64 + 64); l += 32) {
        uint4 r = *(const uint4*)(zs + ((size_t)(nbase + l) << 6) + (p << 3));
        int vfake = l << 17;             // POOLACC reads l from bits 17+
        POOLACC(r, vfake);
    }

    // flush per-thread regs to LDS
    #pragma unroll
    for (int j = 0; j < 8; ++j) {
        if (a0[j] != 0.0f) atomicAdd(&tg[0][p * 8 + j], a0[j]);
        if (a1[j] != 0.0f) atomicAdd(&tg[1][p * 8 + j], a1[j]);
    }
    __syncthreads();

    // block -> global
    for (int i = t; i < GMAX * 64; i += 256) {
        float v = ((float*)tg)[i];
        if (v != 0.0f) {
            int slot2 = i >> 6, c = i & 63;
            int g = gmin + slot2;
            if (g < NGRAPH) atomicAdd(&tpool[g * 64 + c], v);
        }
    }
}

__global__ void finalize_pool(const float* __restrict__ tpool, const int* __restrict__ gstart,
                              const float* __restrict__ bias, float* __restrict__ out) {
    int i = blockIdx.x * 256 + threadIdx.x;
    if (i < NGRAPH * 64) {
        int g = i >> 6, c = i & 63;
        float cnt = (float)(gstart[g + 1] - gstart[g]);
        out[i] = tpool[i] / fmaxf(cnt, 1.0f) + bias[c];
    }
}

// ================= graph boundaries =================
__global__ void gstart_kernel(const int* __restrict__ batch, int* __restrict__ gstart, int n) {
    int g = blockIdx.x * blockDim.x + threadIdx.x;
    if (g > NGRAPH) return;
    if (g == NGRAPH) { gstart[NGRAPH] = n; return; }
    int lo = 0, hi = n;
    while (lo < hi) {
        int mid = (lo + hi) >> 1;
        if (batch[mid] < g) lo = mid + 1; else hi = mid;
    }
    gstart[g] = lo;
}

extern "C" void kernel_launch(void* const* d_in, const int* in_sizes, int n_in,
                              void* d_out, int out_size, void* d_ws, size_t ws_size,
                              hipStream_t stream) {
    const float* x     = (const float*)d_in[0];
    const int*   ei    = (const int*)d_in[1];
    const int*   batch = (const int*)d_in[2];
    const float* W1    = (const float*)d_in[3];
    const float* b1    = (const float*)d_in[4];
    const float* W2    = (const float*)d_in[5];
    const float* b2    = (const float*)d_in[6];
    const float* W3    = (const float*)d_in[7];
    const float* b3    = (const float*)d_in[8];
    float* out = (float*)d_out;

    const int N = N_NODES, E = N_EDGES;
    const int* src = ei;
    const int* dst = ei + E;

    // -------- workspace partition (bytes, 256-aligned; no aliasing) --------
    char* ws = (char*)d_ws;
    float*          dinv    = (float*)         (ws + 0);         //   400000 B
    int*            offsets = (int*)           (ws + 400128);    //   400004 B (N+1)
    int*            csr_src = (int*)           (ws + 800256);    //  6400000 B
    float*          bufA    = (float*)         (ws + 7200384);   // 25600000 B (fp32 layer outputs)
    unsigned short* hbf     = (unsigned short*)(ws + 32800384);  // 12800000 B (bf16 gemm out)
    int*            gstart  = (int*)           (ws + 45600384);  //     2052 B
    int*            perm    = (int*)           (ws + 45602560);  //   400000 B
    int*            scannedD= (int*)           (ws + 46002688);  //    32768 B
    float*          tpool   = (float*)         (ws + 46035712);  //   131072 B
    int*            histT   = (int*)           (ws + 46166784);  //  1601536 B (NB*NWG, bucket-major)
    int*            histWG  = (int*)           (ws + 47768320);  //  1605632 B (NWG*NBP, wg-major)
    int*            blocksumsH = (int*)        (ws + 49373952);  //     2048 B
    int*            ebin    = (int*)           (ws + 49376000);  //  6400000 B (alive until layer 3)

    // -------- bucketed counting sort -> CSR + degree/dinv/offsets --------
    hist_kernel<<<NWG, 256, 0, stream>>>(dst, histWG, E);
    {
        int tilesC = (NB + 31) / 32, tilesR = (NWG + 31) / 32;
        transpose_k<<<tilesC * tilesR, 256, 0, stream>>>(histWG, histT, NWG, NB, NBP, NWG);
    }
    const int nH = NB * NWG;                // 400384
    const int nScanH = (nH + 1023) / 1024;  // 391
    scan_block<<<nScanH, 256, 0, stream>>>(histT, histT, blocksumsH, nH);
    scan_top2<<<1, 256, 0, stream>>>(blocksumsH, nScanH);
    scan_add<<<(nH + 255) / 256, 256, 0, stream>>>(histT, blocksumsH, nH);
    {
        int tilesC = (NWG + 31) / 32, tilesR = (NB + 31) / 32;
        transpose_k<<<tilesC * tilesR, 256, 0, stream>>>(histT, histWG, NB, NWG, NWG, NBP);
    }
    bin_kernel<<<NWG, 256, 0, stream>>>(src, dst, histWG, ebin, E);
    csr_sort2<<<NB, 256, 0, stream>>>(ebin, histT, csr_src, offsets, dinv, E);

    // -------- degree-sorted node permutation --------
    histD_kernel<<<DWG, 256, 0, stream>>>(offsets, scannedD);
    scan_single<<<1, 256, 0, stream>>>(scannedD, MAXD * DWG);
    binD_kernel<<<DWG, 256, 0, stream>>>(offsets, scannedD, perm);

    // -------- graph boundaries + pool accumulator zero --------
    gstart_kernel<<<3, 256, 0, stream>>>(batch, gstart, N);
    hipMemsetAsync(tpool, 0, (size_t)NGRAPH * FDIM * sizeof(float), stream);

    const int gemmGrid   = (N + 63) / 64;
    const int gatherGrid = (N * 8 + 255) / 256;

    // ---- layer 1 ----
    gemm64<<<gemmGrid, 256, 0, stream>>>(x, W1, dinv, hbf, N);
    gather_pn<<<gatherGrid, 256, 0, stream>>>(hbf, csr_src, offsets, perm, dinv, b1, bufA, N, 1);

    // ---- layer 2 ----
    gemm64<<<gemmGrid, 256, 0, stream>>>(bufA, W2, dinv, hbf, N);
    gather_pn<<<gatherGrid, 256, 0, stream>>>(hbf, csr_src, offsets, perm, dinv, b2, bufA, N, 1);

    // ---- layer 3: gemm -> fused gather+pool (pool is linear) ----
    gemm64<<<gemmGrid, 256, 0, stream>>>(bufA, W3, dinv, hbf, N);
    gather_pool<<<NB * 2, 256, 0, stream>>>(hbf, ebin, histT, dinv, batch, tpool, E);
    finalize_pool<<<(NGRAPH * FDIM + 255) / 256, 256, 0, stream>>>(tpool, gstart, b3, out);
}

// Round 15
// 268.352 us; speedup vs baseline: 1.0445x; 1.0445x over previous
//
#include <hip/hip_runtime.h>

#define N_NODES 100000
#define N_EDGES 1600000
#define FDIM 64
#define NGRAPH 512
#define NB 782          // dst buckets of 128 nodes
#define NBP 784         // padded pitch for wg-major hist rows
#define NWG 512         // workgroups in hist/bin passes
#define CHUNK 3125      // E / NWG
#define DWG 64          // workgroups for degree binning
#define DCHUNK ((N_NODES + DWG - 1) / DWG)
#define MAXD 128        // degree clamp for counting sort

__device__ __forceinline__ unsigned short f2bf(float v) {
    unsigned int x = __float_as_uint(v);
    x += 0x7FFF + ((x >> 16) & 1);          // RTNE
    return (unsigned short)(x >> 16);
}
#define BFLO(u) __uint_as_float((u) << 16)
#define BFHI(u) __uint_as_float((u) & 0xFFFF0000u)

// ================= scan kernels =================
__global__ void scan_block(const int* __restrict__ in, int* __restrict__ excl,
                           int* __restrict__ blocksums, int n) {
    __shared__ int lds[256];
    int t = threadIdx.x;
    int base = blockIdx.x * 1024 + t * 4;
    int v0 = (base     < n) ? in[base]     : 0;
    int v1 = (base + 1 < n) ? in[base + 1] : 0;
    int v2 = (base + 2 < n) ? in[base + 2] : 0;
    int v3 = (base + 3 < n) ? in[base + 3] : 0;
    int s = v0 + v1 + v2 + v3;
    lds[t] = s;
    __syncthreads();
    for (int off = 1; off < 256; off <<= 1) {
        int x = (t >= off) ? lds[t - off] : 0;
        __syncthreads();
        lds[t] += x;
        __syncthreads();
    }
    int thrExcl = lds[t] - s;
    if (t == 255) blocksums[blockIdx.x] = lds[255];
    if (base     < n) excl[base]     = thrExcl;
    if (base + 1 < n) excl[base + 1] = thrExcl + v0;
    if (base + 2 < n) excl[base + 2] = thrExcl + v0 + v1;
    if (base + 3 < n) excl[base + 3] = thrExcl + v0 + v1 + v2;
}

__global__ void scan_top2(int* __restrict__ blocksums, int nb) {
    __shared__ int lds[256];
    int t = threadIdx.x;
    int base = t * 4;
    int v0 = (base     < nb) ? blocksums[base]     : 0;
    int v1 = (base + 1 < nb) ? blocksums[base + 1] : 0;
    int v2 = (base + 2 < nb) ? blocksums[base + 2] : 0;
    int v3 = (base + 3 < nb) ? blocksums[base + 3] : 0;
    int s = v0 + v1 + v2 + v3;
    lds[t] = s;
    __syncthreads();
    for (int off = 1; off < 256; off <<= 1) {
        int x = (t >= off) ? lds[t - off] : 0;
        __syncthreads();
        lds[t] += x;
        __syncthreads();
    }
    int excl = lds[t] - s;
    if (base     < nb) blocksums[base]     = excl;
    if (base + 1 < nb) blocksums[base + 1] = excl + v0;
    if (base + 2 < nb) blocksums[base + 2] = excl + v0 + v1;
    if (base + 3 < nb) blocksums[base + 3] = excl + v0 + v1 + v2;
}

__global__ void scan_add(int* __restrict__ out, const int* __restrict__ blocksums, int n) {
    int i = blockIdx.x * blockDim.x + threadIdx.x;
    if (i < n) out[i] += blocksums[i >> 10];
}

// single-block exclusive scan for n = 8192 (degree histogram)
__global__ __launch_bounds__(256) void scan_single(int* __restrict__ data, int n) {
    __shared__ int lds[256];
    int t = threadIdx.x;
    int loc[32];
    int base = t * 32;
    int s = 0;
    #pragma unroll
    for (int j = 0; j < 32; ++j) { loc[j] = (base + j < n) ? data[base + j] : 0; s += loc[j]; }
    lds[t] = s;
    __syncthreads();
    for (int off = 1; off < 256; off <<= 1) {
        int x = (t >= off) ? lds[t - off] : 0;
        __syncthreads();
        lds[t] += x;
        __syncthreads();
    }
    int run = lds[t] - s;
    #pragma unroll
    for (int j = 0; j < 32; ++j) {
        int v = loc[j];
        if (base + j < n) data[base + j] = run;
        run += v;
    }
}

// ================= 32x32 LDS transpose =================
__global__ __launch_bounds__(256) void transpose_k(const int* __restrict__ src, int* __restrict__ dst,
                                                   int R, int C, int spitch, int dpitch) {
    __shared__ int tile[32][33];
    int tilesC = (C + 31) >> 5;
    int bx = blockIdx.x % tilesC;
    int by = blockIdx.x / tilesC;
    int tx = threadIdx.x & 31, ty = threadIdx.x >> 5;
    int c = bx * 32 + tx;
    #pragma unroll
    for (int j = 0; j < 32; j += 8) {
        int r = by * 32 + ty + j;
        if (r < R && c < C) tile[ty + j][tx] = src[r * spitch + c];
    }
    __syncthreads();
    int rT = by * 32 + tx;
    #pragma unroll
    for (int j = 0; j < 32; j += 8) {
        int cT = bx * 32 + ty + j;
        if (cT < C && rT < R) dst[cT * dpitch + rT] = tile[tx][ty + j];
    }
}

// ================= pass A: per-wg bucket histogram (wg-major, coalesced) =================
__global__ __launch_bounds__(256) void hist_kernel(const int* __restrict__ dst,
                                                   int* __restrict__ histWG, int E) {
    __shared__ int h[NB];
    int t = threadIdx.x, wg = blockIdx.x;
    for (int i = t; i < NB; i += 256) h[i] = 0;
    __syncthreads();
    int beg = wg * CHUNK, end = min(beg + CHUNK, E);
    for (int i = beg + t; i < end; i += 256) atomicAdd(&h[dst[i] >> 7], 1);
    __syncthreads();
    for (int i = t; i < NB; i += 256) histWG[wg * NBP + i] = h[i];
}

// ================= pass B: binned append =================
__global__ __launch_bounds__(256) void bin_kernel(const int* __restrict__ src,
                                                  const int* __restrict__ dst,
                                                  const int* __restrict__ baseWG,
                                                  int* __restrict__ ebin, int E) {
    __shared__ int base[NB];
    __shared__ int cur[NB];
    int t = threadIdx.x, wg = blockIdx.x;
    for (int i = t; i < NB; i += 256) { base[i] = baseWG[wg * NBP + i]; cur[i] = 0; }
    __syncthreads();
    int beg = wg * CHUNK, end = min(beg + CHUNK, E);
    for (int i = beg + t * 2; i < end; i += 512) {
        int d0 = dst[i], s0 = src[i];
        int b0 = d0 >> 7;
        int p0 = base[b0] + atomicAdd(&cur[b0], 1);
        ebin[p0] = ((d0 & 127) << 17) | s0;
        if (i + 1 < end) {
            int d1 = dst[i + 1], s1 = src[i + 1];
            int b1 = d1 >> 7;
            int p1 = base[b1] + atomicAdd(&cur[b1], 1);
            ebin[p1] = ((d1 & 127) << 17) | s1;
        }
    }
}

// ================= pass C: per-bucket sort + degree + dinv + offsets =================
__global__ __launch_bounds__(256) void csr_sort2(const int* __restrict__ ebin,
                                                 const int* __restrict__ scannedT,
                                                 int* __restrict__ csr_src,
                                                 int* __restrict__ offsets,
                                                 float* __restrict__ dinv, int E) {
    __shared__ int cnt[128];
    __shared__ int seg[128];
    __shared__ int cur[128];
    __shared__ int buf[4352];
    int t = threadIdx.x, b = blockIdx.x;
    int nbase = b << 7;
    int nodes = min(128, N_NODES - nbase);
    int bstart = scannedT[b * NWG];
    int bend = (b == NB - 1) ? E : scannedT[(b + 1) * NWG];
    if (t < 128) cnt[t] = 0;
    __syncthreads();
    for (int i = bstart + t; i < bend; i += 256) atomicAdd(&cnt[ebin[i] >> 17], 1);
    __syncthreads();
    if (t < 128) seg[t] = cnt[t];
    __syncthreads();
    for (int off = 1; off < 128; off <<= 1) {
        int v = 0;
        if (t < 128 && t >= off) v = seg[t - off];
        __syncthreads();
        if (t < 128) seg[t] += v;
        __syncthreads();
    }
    if (t < nodes) {
        int excl = seg[t] - cnt[t];
        offsets[nbase + t] = bstart + excl;
        dinv[nbase + t] = rsqrtf((float)cnt[t] + 1.0f);   // +1 self loop
        cur[t] = excl;
    }
    if (b == 0 && t == 0) offsets[N_NODES] = E;
    __syncthreads();
    for (int i = bstart + t; i < bend; i += 256) {
        int v = ebin[i];
        int p = atomicAdd(&cur[v >> 17], 1);
        buf[p] = v & 0x1FFFF;
    }
    __syncthreads();
    int span = bend - bstart;
    for (int i = t; i < span; i += 256) csr_src[bstart + i] = buf[i];
}

// ================= degree counting sort =================
__global__ __launch_bounds__(256) void histD_kernel(const int* __restrict__ offsets,
                                                    int* __restrict__ histD) {
    __shared__ int h[MAXD];
    int t = threadIdx.x, wg = blockIdx.x;
    if (t < MAXD) h[t] = 0;
    __syncthreads();
    int beg = wg * DCHUNK, end = min(beg + DCHUNK, N_NODES);
    for (int i = beg + t; i < end; i += 256) {
        int d = min(offsets[i + 1] - offsets[i], MAXD - 1);
        atomicAdd(&h[d], 1);
    }
    __syncthreads();
    if (t < MAXD) histD[t * DWG + wg] = h[t];
}

__global__ __launch_bounds__(256) void binD_kernel(const int* __restrict__ offsets,
                                                   const int* __restrict__ scannedD,
                                                   int* __restrict__ perm) {
    __shared__ int base[MAXD];
    __shared__ int cur[MAXD];
    int t = threadIdx.x, wg = blockIdx.x;
    if (t < MAXD) { base[t] = scannedD[t * DWG + wg]; cur[t] = 0; }
    __syncthreads();
    int beg = wg * DCHUNK, end = min(beg + DCHUNK, N_NODES);
    for (int i = beg + t; i < end; i += 256) {
        int d = min(offsets[i + 1] - offsets[i], MAXD - 1);
        int pos = base[d] + atomicAdd(&cur[d], 1);
        perm[pos] = i;
    }
}

// ================= fp32 GEMM (register-tiled 4x4) -> bf16 =================
__global__ __launch_bounds__(256) void gemm64(const float* __restrict__ X,
                                              const float* __restrict__ W,
                                              const float* __restrict__ dinv,
                                              unsigned short* __restrict__ Hout, int n) {
    __shared__ float Ws[64 * 68];
    __shared__ float Xs[64 * 68];
    int t = threadIdx.x;
    int r0 = blockIdx.x * 64;

    #pragma unroll
    for (int kk = 0; kk < 16; ++kk) {
        int idx = t + kk * 256;
        int r = idx >> 6, c = idx & 63;
        Ws[r * 68 + c] = W[idx];
        float v = (r0 + r < n) ? X[(size_t)(r0 + r) * FDIM + c] : 0.0f;
        Xs[c * 68 + r] = v;
    }
    __syncthreads();

    int rg = (t >> 4) << 2;
    int cg = (t & 15) << 2;
    float4 acc0 = {0, 0, 0, 0}, acc1 = {0, 0, 0, 0};
    float4 acc2 = {0, 0, 0, 0}, acc3 = {0, 0, 0, 0};

    #pragma unroll 8
    for (int k = 0; k < 64; ++k) {
        float4 xv = *(const float4*)&Xs[k * 68 + rg];
        float4 wv = *(const float4*)&Ws[k * 68 + cg];
        acc0.x += xv.x * wv.x; acc0.y += xv.x * wv.y; acc0.z += xv.x * wv.z; acc0.w += xv.x * wv.w;
        acc1.x += xv.y * wv.x; acc1.y += xv.y * wv.y; acc1.z += xv.y * wv.z; acc1.w += xv.y * wv.w;
        acc2.x += xv.z * wv.x; acc2.y += xv.z * wv.y; acc2.z += xv.z * wv.z; acc2.w += xv.z * wv.w;
        acc3.x += xv.w * wv.x; acc3.y += xv.w * wv.y; acc3.z += xv.w * wv.z; acc3.w += xv.w * wv.w;
    }

    float4 accs[4] = {acc0, acc1, acc2, acc3};
    #pragma unroll
    for (int i = 0; i < 4; ++i) {
        int row = r0 + rg + i;
        if (row < n) {
            float sc = dinv[row];
            unsigned int u0 = (unsigned int)f2bf(accs[i].x * sc) | ((unsigned int)f2bf(accs[i].y * sc) << 16);
            unsigned int u1 = (unsigned int)f2bf(accs[i].z * sc) | ((unsigned int)f2bf(accs[i].w * sc) << 16);
            *(uint2*)&Hout[(size_t)row * FDIM + cg] = make_uint2(u0, u1);
        }
    }
}

// ================= gather, 8 lanes own one node, unroll-8 =================
#define ACC8(v) do { \
    a0 += BFLO(v.x); a1 += BFHI(v.x); a2 += BFLO(v.y); a3 += BFHI(v.y); \
    a4 += BFLO(v.z); a5 += BFHI(v.z); a6 += BFLO(v.w); a7 += BFHI(v.w); } while (0)

__global__ __launch_bounds__(256) void gather_pn(const unsigned short* __restrict__ hs,
                                                 const int* __restrict__ csr_src,
                                                 const int* __restrict__ offsets,
                                                 const int* __restrict__ perm,
                                                 const float* __restrict__ dinv,
                                                 const float* __restrict__ bias,
                                                 float* __restrict__ outb,
                                                 int n, int do_relu) {
    int slot = (blockIdx.x * 256 + threadIdx.x) >> 3;
    int p = threadIdx.x & 7;
    if (slot >= n) return;
    int node = perm[slot];
    int beg = offsets[node], end = offsets[node + 1];

    float a0 = 0, a1 = 0, a2 = 0, a3 = 0, a4 = 0, a5 = 0, a6 = 0, a7 = 0;
    int k = beg;
    for (; k + 7 < end; k += 8) {
        int s0 = csr_src[k],     s1 = csr_src[k + 1], s2 = csr_src[k + 2], s3 = csr_src[k + 3];
        int s4 = csr_src[k + 4], s5 = csr_src[k + 5], s6 = csr_src[k + 6], s7 = csr_src[k + 7];
        uint4 v0 = *(const uint4*)(hs + ((size_t)s0 << 6) + (p << 3));
        uint4 v1 = *(const uint4*)(hs + ((size_t)s1 << 6) + (p << 3));
        uint4 v2 = *(const uint4*)(hs + ((size_t)s2 << 6) + (p << 3));
        uint4 v3 = *(const uint4*)(hs + ((size_t)s3 << 6) + (p << 3));
        uint4 v4 = *(const uint4*)(hs + ((size_t)s4 << 6) + (p << 3));
        uint4 v5 = *(const uint4*)(hs + ((size_t)s5 << 6) + (p << 3));
        uint4 v6 = *(const uint4*)(hs + ((size_t)s6 << 6) + (p << 3));
        uint4 v7 = *(const uint4*)(hs + ((size_t)s7 << 6) + (p << 3));
        ACC8(v0); ACC8(v1); ACC8(v2); ACC8(v3);
        ACC8(v4); ACC8(v5); ACC8(v6); ACC8(v7);
    }
    for (; k + 3 < end; k += 4) {
        int s0 = csr_src[k], s1 = csr_src[k + 1], s2 = csr_src[k + 2], s3 = csr_src[k + 3];
        uint4 v0 = *(const uint4*)(hs + ((size_t)s0 << 6) + (p << 3));
        uint4 v1 = *(const uint4*)(hs + ((size_t)s1 << 6) + (p << 3));
        uint4 v2 = *(const uint4*)(hs + ((size_t)s2 << 6) + (p << 3));
        uint4 v3 = *(const uint4*)(hs + ((size_t)s3 << 6) + (p << 3));
        ACC8(v0); ACC8(v1); ACC8(v2); ACC8(v3);
    }
    for (; k < end; ++k) {
        int s0 = csr_src[k];
        uint4 v0 = *(const uint4*)(hs + ((size_t)s0 << 6) + (p << 3));
        ACC8(v0);
    }
    // self-loop row
    uint4 sv = *(const uint4*)(hs + ((size_t)node << 6) + (p << 3));
    float dd = dinv[node];
    int fb = p << 3;
    const float4* bp = (const float4*)(bias + fb);
    float4 bv0 = bp[0], bv1 = bp[1];
    float o0 = dd * (a0 + BFLO(sv.x)) + bv0.x;
    float o1 = dd * (a1 + BFHI(sv.x)) + bv0.y;
    float o2 = dd * (a2 + BFLO(sv.y)) + bv0.z;
    float o3 = dd * (a3 + BFHI(sv.y)) + bv0.w;
    float o4 = dd * (a4 + BFLO(sv.z)) + bv1.x;
    float o5 = dd * (a5 + BFHI(sv.z)) + bv1.y;
    float o6 = dd * (a6 + BFLO(sv.w)) + bv1.z;
    float o7 = dd * (a7 + BFHI(sv.w)) + bv1.w;
    if (do_relu) {
        o0 = fmaxf(o0, 0.0f); o1 = fmaxf(o1, 0.0f); o2 = fmaxf(o2, 0.0f); o3 = fmaxf(o3, 0.0f);
        o4 = fmaxf(o4, 0.0f); o5 = fmaxf(o5, 0.0f); o6 = fmaxf(o6, 0.0f); o7 = fmaxf(o7, 0.0f);
    }
    float4* op = (float4*)(outb + (size_t)node * FDIM + fb);
    op[0] = make_float4(o0, o1, o2, o3);
    op[1] = make_float4(o4, o5, o6, o7);
}

// ================= pooling (batch sorted -> segmented reduction) =================
__global__ void gstart_kernel(const int* __restrict__ batch, int* __restrict__ gstart, int n) {
    int g = blockIdx.x * blockDim.x + threadIdx.x;
    if (g > NGRAPH) return;
    if (g == NGRAPH) { gstart[NGRAPH] = n; return; }
    int lo = 0, hi = n;
    while (lo < hi) {
        int mid = (lo + hi) >> 1;
        if (batch[mid] < g) lo = mid + 1; else hi = mid;
    }
    gstart[g] = lo;
}

__global__ __launch_bounds__(256) void pool2(const float* __restrict__ h,
                                             const int* __restrict__ gstart,
                                             float* __restrict__ out) {
    __shared__ float red[4][64];
    int g = blockIdx.x;
    int beg = gstart[g], end = gstart[g + 1];
    int w = threadIdx.x >> 6, lane = threadIdx.x & 63;
    float acc = 0.0f;
    for (int i = beg + w; i < end; i += 4)
        acc += h[(size_t)i * FDIM + lane];
    red[w][lane] = acc;
    __syncthreads();
    if (w == 0) {
        float tot = red[0][lane] + red[1][lane] + red[2][lane] + red[3][lane];
        float cnt = (float)(end - beg);
        out[(size_t)g * FDIM + lane] = tot / fmaxf(cnt, 1.0f);
    }
}

extern "C" void kernel_launch(void* const* d_in, const int* in_sizes, int n_in,
                              void* d_out, int out_size, void* d_ws, size_t ws_size,
                              hipStream_t stream) {
    const float* x     = (const float*)d_in[0];
    const int*   ei    = (const int*)d_in[1];
    const int*   batch = (const int*)d_in[2];
    const float* W1    = (const float*)d_in[3];
    const float* b1    = (const float*)d_in[4];
    const float* W2    = (const float*)d_in[5];
    const float* b2    = (const float*)d_in[6];
    const float* W3    = (const float*)d_in[7];
    const float* b3    = (const float*)d_in[8];
    float* out = (float*)d_out;

    const int N = N_NODES, E = N_EDGES;
    const int* src = ei;
    const int* dst = ei + E;

    // -------- workspace partition (bytes, 256-aligned; no aliasing) --------
    char* ws = (char*)d_ws;
    float*          dinv    = (float*)         (ws + 0);         //   400000 B
    int*            offsets = (int*)           (ws + 400128);    //   400004 B (N+1)
    int*            csr_src = (int*)           (ws + 800256);    //  6400000 B
    float*          bufA    = (float*)         (ws + 7200384);   // 25600000 B (fp32 layer outputs)
    unsigned short* hbf     = (unsigned short*)(ws + 32800384);  // 12800000 B (bf16 gemm out)
    int*            gstart  = (int*)           (ws + 45600384);  //     2052 B
    int*            perm    = (int*)           (ws + 45602560);  //   400000 B
    int*            scannedD= (int*)           (ws + 46002688);  //    32768 B
    int*            histT   = (int*)           (ws + 46166784);  //  1601536 B (NB*NWG, bucket-major)
    int*            histWG  = (int*)           (ws + 47768320);  //  1605632 B (NWG*NBP, wg-major)
    int*            blocksumsH = (int*)        (ws + 49373952);  //     2048 B
    int*            ebin    = (int*)           (ws + 49376000);  //  6400000 B

    // -------- bucketed counting sort -> CSR + degree/dinv/offsets --------
    hist_kernel<<<NWG, 256, 0, stream>>>(dst, histWG, E);
    {
        int tilesC = (NB + 31) / 32, tilesR = (NWG + 31) / 32;
        transpose_k<<<tilesC * tilesR, 256, 0, stream>>>(histWG, histT, NWG, NB, NBP, NWG);
    }
    const int nH = NB * NWG;                // 400384
    const int nScanH = (nH + 1023) / 1024;  // 391
    scan_block<<<nScanH, 256, 0, stream>>>(histT, histT, blocksumsH, nH);
    scan_top2<<<1, 256, 0, stream>>>(blocksumsH, nScanH);
    scan_add<<<(nH + 255) / 256, 256, 0, stream>>>(histT, blocksumsH, nH);
    {
        int tilesC = (NWG + 31) / 32, tilesR = (NB + 31) / 32;
        transpose_k<<<tilesC * tilesR, 256, 0, stream>>>(histT, histWG, NB, NWG, NWG, NBP);
    }
    bin_kernel<<<NWG, 256, 0, stream>>>(src, dst, histWG, ebin, E);
    csr_sort2<<<NB, 256, 0, stream>>>(ebin, histT, csr_src, offsets, dinv, E);

    // -------- degree-sorted node permutation --------
    histD_kernel<<<DWG, 256, 0, stream>>>(offsets, scannedD);
    scan_single<<<1, 256, 0, stream>>>(scannedD, MAXD * DWG);
    binD_kernel<<<DWG, 256, 0, stream>>>(offsets, scannedD, perm);

    // -------- graph boundaries --------
    gstart_kernel<<<3, 256, 0, stream>>>(batch, gstart, N);

    const int gemmGrid   = (N + 63) / 64;
    const int gatherGrid = (N * 8 + 255) / 256;

    // ---- layer 1 ----
    gemm64<<<gemmGrid, 256, 0, stream>>>(x, W1, dinv, hbf, N);
    gather_pn<<<gatherGrid, 256, 0, stream>>>(hbf, csr_src, offsets, perm, dinv, b1, bufA, N, 1);

    // ---- layer 2 ----
    gemm64<<<gemmGrid, 256, 0, stream>>>(bufA, W2, dinv, hbf, N);
    gather_pn<<<gatherGrid, 256, 0, stream>>>(hbf, csr_src, offsets, perm, dinv, b2, bufA, N, 1);

    // ---- layer 3 ----
    gemm64<<<gemmGrid, 256, 0, stream>>>(bufA, W3, dinv, hbf, N);
    gather_pn<<<gatherGrid, 256, 0, stream>>>(hbf, csr_src, offsets, perm, dinv, b3, bufA, N, 0);

    // ---- global mean pool (no atomics) ----
    pool2<<<NGRAPH, 256, 0, stream>>>(bufA, gstart, out);
}